// Round 1
// baseline (452.284 us; speedup 1.0000x reference)
//
#include <hip/hip_runtime.h>

#define BINS 10

// ---------------------------------------------------------------------------
// Pass 1: per-bin partial log-sums + nonempty bitmask.
// Each thread keeps 10 register accumulators (static indices only) and a
// 10-bit mask; wave shfl-reduce -> LDS cross-wave -> 1 atomic per bin/block.
// ---------------------------------------------------------------------------
__global__ __launch_bounds__(256) void ghm_partial_kernel(
    const float* __restrict__ pre,
    const float* __restrict__ gt,
    float* __restrict__ bin_sums,        // [BINS] in d_ws, pre-zeroed
    unsigned int* __restrict__ mask_out, // 1 uint in d_ws, pre-zeroed
    int n4,                              // number of float4 elements
    int tot)                             // total scalar elements
{
    float s[BINS];
#pragma unroll
    for (int b = 0; b < BINS; ++b) s[b] = 0.0f;
    unsigned int mask = 0u;

    const float4* __restrict__ p4 = reinterpret_cast<const float4*>(pre);
    const float4* __restrict__ g4 = reinterpret_cast<const float4*>(gt);

    const int stride = gridDim.x * blockDim.x;
    for (int i = blockIdx.x * blockDim.x + threadIdx.x; i < n4; i += stride) {
        float4 p = p4[i];
        float4 t = g4[i];
        float pv[4] = {p.x, p.y, p.z, p.w};
        float tv[4] = {t.x, t.y, t.z, t.w};
#pragma unroll
        for (int e = 0; e < 4; ++e) {
            float pe = pv[e];
            float te = tv[e];
            float g = fabsf(pe - te);
            int bin = (int)(g * 10.0f);       // trunc == floor (g >= 0)
            bin = bin > (BINS - 1) ? (BINS - 1) : bin;
            // pos (gt==1): log(pre); neg: log1p(-pre) ~= log(1-pre).
            // One transcendental: select the argument, then logf.
            float arg = (te == 1.0f) ? pe : (1.0f - pe);
            float logterm = logf(arg);
            mask |= (1u << bin);
#pragma unroll
            for (int b = 0; b < BINS; ++b)
                s[b] += (bin == b) ? logterm : 0.0f;
        }
    }

    // Scalar tail (tot % 4), handled by first few threads of block 0.
    const int rem_start = n4 * 4;
    const int rem = tot - rem_start;
    if (blockIdx.x == 0 && threadIdx.x < rem) {
        float pe = pre[rem_start + threadIdx.x];
        float te = gt[rem_start + threadIdx.x];
        float g = fabsf(pe - te);
        int bin = (int)(g * 10.0f);
        bin = bin > (BINS - 1) ? (BINS - 1) : bin;
        float arg = (te == 1.0f) ? pe : (1.0f - pe);
        float logterm = logf(arg);
        mask |= (1u << bin);
#pragma unroll
        for (int b = 0; b < BINS; ++b)
            s[b] += (bin == b) ? logterm : 0.0f;
    }

    // ---- wave (64-lane) butterfly reduce ----
#pragma unroll
    for (int b = 0; b < BINS; ++b) {
#pragma unroll
        for (int off = 32; off >= 1; off >>= 1)
            s[b] += __shfl_down(s[b], off, 64);
    }
#pragma unroll
    for (int off = 32; off >= 1; off >>= 1)
        mask |= __shfl_down(mask, off, 64);

    // ---- cross-wave via LDS (256 threads = 4 waves) ----
    __shared__ float ls[4][BINS];
    __shared__ unsigned int lm[4];
    const int lane = threadIdx.x & 63;
    const int wave = threadIdx.x >> 6;
    if (lane == 0) {
#pragma unroll
        for (int b = 0; b < BINS; ++b) ls[wave][b] = s[b];
        lm[wave] = mask;
    }
    __syncthreads();
    if (threadIdx.x == 0) {
        unsigned int m = lm[0] | lm[1] | lm[2] | lm[3];
        atomicOr(mask_out, m);
#pragma unroll
        for (int b = 0; b < BINS; ++b) {
            float v = ls[0][b] + ls[1][b] + ls[2][b] + ls[3][b];
            atomicAdd(&bin_sums[b], v);
        }
    }
}

// ---------------------------------------------------------------------------
// Pass 2: trivial finalize. loss = (sum_b S_b * w_b) / n / tot
// ---------------------------------------------------------------------------
__global__ void ghm_finalize_kernel(
    const float* __restrict__ bin_sums,
    const unsigned int* __restrict__ mask_in,
    const float* __restrict__ acc_sum,
    float* __restrict__ out,
    float tot)
{
    if (threadIdx.x == 0 && blockIdx.x == 0) {
        unsigned int mask = *mask_in;
        int n = __popc(mask & ((1u << BINS) - 1u));
        float total = 0.0f;
#pragma unroll
        for (int b = 0; b < BINS; ++b) {
            float w = ((mask >> b) & 1u) ? (tot / acc_sum[b]) : 0.0f;
            total += bin_sums[b] * w;
        }
        if (n > 0) total /= (float)n;
        out[0] = total / tot;
    }
}

extern "C" void kernel_launch(void* const* d_in, const int* in_sizes, int n_in,
                              void* d_out, int out_size, void* d_ws, size_t ws_size,
                              hipStream_t stream) {
    const float* pre     = (const float*)d_in[0];
    const float* gt      = (const float*)d_in[1];
    const float* acc_sum = (const float*)d_in[2];
    float* out = (float*)d_out;

    const int tot = in_sizes[0];     // B*C*H*W = 20,971,520
    const int n4  = tot / 4;

    float* bin_sums = (float*)d_ws;
    unsigned int* mask_ws = (unsigned int*)((char*)d_ws + BINS * sizeof(float));

    // ws is poisoned 0xAA before every timed launch -> zero what we use.
    hipMemsetAsync(d_ws, 0, BINS * sizeof(float) + sizeof(unsigned int), stream);

    const int threads = 256;
    int blocks = (n4 + threads - 1) / threads;
    if (blocks > 2048) blocks = 2048;   // grid-stride the rest (G11)

    ghm_partial_kernel<<<blocks, threads, 0, stream>>>(
        pre, gt, bin_sums, mask_ws, n4, tot);
    ghm_finalize_kernel<<<1, 64, 0, stream>>>(
        bin_sums, mask_ws, acc_sum, out, (float)tot);
}

// Round 5
// 186.506 us; speedup vs baseline: 2.4250x; 2.4250x over previous
//
#include <hip/hip_runtime.h>

#define BINS 10
#define NTHR 256
#define MAXBLK 2048

// ---------------------------------------------------------------------------
// loss = ( sum_e log2(arg_e) * (ln2/acc_sum[bin_e]) ) / n
//   arg_e = (gt==1) ? pre : (1-pre);  bin_e = min(floor(10*|pre-gt|), 9)
//   n = popcount(nonempty-bin mask)
// Empty bins contribute zero sum automatically, so the where(nonempty,...)
// gating in the reference is a no-op for the weighted sum; `tot` cancels.
//
// Pass 1: per-block partial weighted log-sum + 10-bit nonempty mask,
//         written to a PRIVATE slot per block (no global atomics).
// Pass 2: 1-block reduction of the 2048 slots -> out scalar.
// ---------------------------------------------------------------------------
__global__ __launch_bounds__(NTHR) void ghm_partial_kernel(
    const float* __restrict__ pre,
    const float* __restrict__ gt,
    const float* __restrict__ acc_sum,
    float* __restrict__ blk_sum,          // [gridDim.x] in d_ws
    unsigned int* __restrict__ blk_mask,  // [gridDim.x] in d_ws
    int n4,                               // float4 count
    int tot)                              // scalar count
{
    // ln2/acc_sum[b] table in LDS: 10 consecutive dwords -> 10 distinct banks,
    // per-element gather is conflict-free (same-address lanes broadcast).
    __shared__ float wtab[BINS];
    if (threadIdx.x < BINS)
        wtab[threadIdx.x] = 0.69314718055994531f / acc_sum[threadIdx.x];
    __syncthreads();

    float acc = 0.0f;
    unsigned int mask = 0u;

    const float4* __restrict__ p4 = reinterpret_cast<const float4*>(pre);
    const float4* __restrict__ g4 = reinterpret_cast<const float4*>(gt);

    const int stride = gridDim.x * blockDim.x;
    for (int i = blockIdx.x * blockDim.x + threadIdx.x; i < n4; i += stride) {
        float4 p = p4[i];
        float4 t = g4[i];
        float pv[4] = {p.x, p.y, p.z, p.w};
        float tv[4] = {t.x, t.y, t.z, t.w};
#pragma unroll
        for (int e = 0; e < 4; ++e) {
            float pe = pv[e];
            float te = tv[e];
            float g = fabsf(pe - te);
            int bin = (int)(g * 10.0f);              // g>=0: trunc==floor
            bin = bin > (BINS - 1) ? (BINS - 1) : bin;
            mask |= (1u << bin);
            float arg = (te == 1.0f) ? pe : (1.0f - pe);
            // native v_log_f32 (log2); ln2 folded into wtab
            acc = fmaf(__log2f(arg), wtab[bin], acc);
        }
    }

    // Scalar tail (tot % 4) via first threads of block 0.
    const int rs = n4 * 4;
    const int rem = tot - rs;
    if (blockIdx.x == 0 && (int)threadIdx.x < rem) {
        float pe = pre[rs + threadIdx.x];
        float te = gt[rs + threadIdx.x];
        float g = fabsf(pe - te);
        int bin = (int)(g * 10.0f);
        bin = bin > (BINS - 1) ? (BINS - 1) : bin;
        mask |= (1u << bin);
        float arg = (te == 1.0f) ? pe : (1.0f - pe);
        acc = fmaf(__log2f(arg), wtab[bin], acc);
    }

    // wave (64-lane) butterfly reduce
#pragma unroll
    for (int off = 32; off >= 1; off >>= 1) {
        acc  += __shfl_down(acc, off, 64);
        mask |= (unsigned int)__shfl_down((int)mask, off, 64);
    }

    // cross-wave via LDS (4 waves)
    __shared__ float ls[4];
    __shared__ unsigned int lm[4];
    const int lane = threadIdx.x & 63;
    const int wave = threadIdx.x >> 6;
    if (lane == 0) { ls[wave] = acc; lm[wave] = mask; }
    __syncthreads();
    if (threadIdx.x == 0) {
        blk_sum[blockIdx.x]  = ls[0] + ls[1] + ls[2] + ls[3];
        blk_mask[blockIdx.x] = lm[0] | lm[1] | lm[2] | lm[3];
    }
}

__global__ __launch_bounds__(NTHR) void ghm_finalize_kernel(
    const float* __restrict__ blk_sum,
    const unsigned int* __restrict__ blk_mask,
    float* __restrict__ out,
    int nblk)
{
    float acc = 0.0f;
    unsigned int mask = 0u;
    for (int i = threadIdx.x; i < nblk; i += NTHR) {
        acc  += blk_sum[i];
        mask |= blk_mask[i];
    }
#pragma unroll
    for (int off = 32; off >= 1; off >>= 1) {
        acc  += __shfl_down(acc, off, 64);
        mask |= (unsigned int)__shfl_down((int)mask, off, 64);
    }
    __shared__ float ls[4];
    __shared__ unsigned int lm[4];
    const int lane = threadIdx.x & 63;
    const int wave = threadIdx.x >> 6;
    if (lane == 0) { ls[wave] = acc; lm[wave] = mask; }
    __syncthreads();
    if (threadIdx.x == 0) {
        float total = ls[0] + ls[1] + ls[2] + ls[3];
        unsigned int m = lm[0] | lm[1] | lm[2] | lm[3];
        int n = __popc(m & ((1u << BINS) - 1u));
        out[0] = (n > 0) ? (total / (float)n) : total;
    }
}

extern "C" void kernel_launch(void* const* d_in, const int* in_sizes, int n_in,
                              void* d_out, int out_size, void* d_ws, size_t ws_size,
                              hipStream_t stream) {
    const float* pre     = (const float*)d_in[0];
    const float* gt      = (const float*)d_in[1];
    const float* acc_sum = (const float*)d_in[2];
    float* out = (float*)d_out;

    const int tot = in_sizes[0];   // 20,971,520
    const int n4  = tot / 4;

    int blocks = (n4 + NTHR - 1) / NTHR;
    if (blocks > MAXBLK) blocks = MAXBLK;
    if (blocks < 1) blocks = 1;

    float* blk_sum = (float*)d_ws;
    unsigned int* blk_mask = (unsigned int*)((char*)d_ws + MAXBLK * sizeof(float));

    ghm_partial_kernel<<<blocks, NTHR, 0, stream>>>(
        pre, gt, acc_sum, blk_sum, blk_mask, n4, tot);
    ghm_finalize_kernel<<<1, NTHR, 0, stream>>>(
        blk_sum, blk_mask, out, blocks);
}